// Round 4
// baseline (860.584 us; speedup 1.0000x reference)
//
#include <hip/hip_runtime.h>
#include <float.h>

// Problem constants (from reference file)
constexpr int C   = 512;           // DIM_CODES
constexpr int K   = 512;           // DICT_SIZE
constexpr int E   = 16;           // EMBED_DIM
constexpr int B   = 512;           // BATCH
constexpr int RPB = 256;           // rows (batches) per block = blockDim
constexpr int MUS = C * E;         // 8192, mu row stride

__device__ __forceinline__ float fdot4(const float4 a, const float4 b, float acc) {
    acc = fmaf(a.x, b.x, acc);
    acc = fmaf(a.y, b.y, acc);
    acc = fmaf(a.z, b.z, acc);
    acc = fmaf(a.w, b.w, acc);
    return acc;
}
__device__ __forceinline__ double ddot4(const float4 a, const float4 b, double acc) {
    return acc + ((double)a.x * b.x + (double)a.y * b.y
                + (double)a.z * b.z + (double)a.w * b.w);
}
__device__ __forceinline__ double dnrm4(const float4 a, double acc) {
    return acc + ((double)a.x * a.x + (double)a.y * a.y
                + (double)a.z * a.z + (double)a.w * a.w);
}

// Lane <-> row mapping: thread t of block (c, y) owns batch row b = y*256+t.
// It streams all 512 codes (wave-uniform address -> scalar/L1-broadcast
// loads) keeping a running per-lane argmin in registers: NO cross-lane ops.
// Per-code norms are precomputed once per block into LDS (2 KB broadcast
// reads). one_hot is written as an early coalesced zero-fill (overlaps the
// k-loop with the 512 MB store stream) + one 4 B scatter of 1.0 per row,
// ordered via s_waitcnt vmcnt(0).
//
// __launch_bounds__(256,4): live set ~70-90 VGPRs, cap 128 -> no spill
// (round-2's lesson), 16 waves/CU for latency hiding (round-3's lesson:
// (256,1) let VGPRs balloon -> 1 wave/EU -> regression).
__launch_bounds__(256, 4)
__global__ void vq_kernel(const float* __restrict__ mu,
                          const float* __restrict__ dict,
                          float* __restrict__ z,
                          float* __restrict__ zq,
                          float* __restrict__ oh)
{
    const int c    = blockIdx.x;
    const int tid  = threadIdx.x;
    const int lane = tid & 63;
    const int b    = blockIdx.y * RPB + tid;   // this thread's batch row

    __shared__ float nd_s[K];                  // per-code ||d||^2, 2 KB

    const float* __restrict__ dbase = dict + (size_t)c * K * E;

    // ---- this thread's mu row -> registers (issue early; lane-private
    //      64 B = exactly one cache line, fully consumed)
    const float4* mp = reinterpret_cast<const float4*>(mu + (size_t)b * MUS + c * E);
    const float4 m0 = mp[0], m1 = mp[1], m2 = mp[2], m3 = mp[3];

    // ---- preamble: per-code squared norms into LDS (2 codes per thread)
#pragma unroll
    for (int rep = 0; rep < 2; ++rep) {
        const int k = tid + rep * 256;
        const float4* p = reinterpret_cast<const float4*>(dbase + (size_t)k * E);
        const float4 a0 = p[0], a1 = p[1], a2 = p[2], a3 = p[3];
        float s = fdot4(a0, a0, 0.0f);
        s = fdot4(a1, a1, s);
        s = fdot4(a2, a2, s);
        s = fdot4(a3, a3, s);
        nd_s[k] = s;
    }

    // ---- zero-fill this wave's 64 one_hot rows NOW: independent of the
    //      argmin, gets the dominant 512 MB store stream going while the
    //      k-loop computes. Each store inst = contiguous 1 KB across the wave.
    {
        const size_t rowstride = (size_t)C * K / 4;   // one b-row, float4 units
        float4* p = reinterpret_cast<float4*>(
            oh + ((size_t)(blockIdx.y * RPB + (tid & ~63)) * C + c) * K) + lane;
        const float4 z4 = make_float4(0.f, 0.f, 0.f, 0.f);
#pragma unroll 4
        for (int r = 0; r < 64; ++r) {
            p[0]  = z4;    // floats [lane*4,    lane*4+4)
            p[64] = z4;    // floats [256+lane*4, ...)
            p += rowstride;
        }
    }

    __syncthreads();

    // ---- k-loop: per-lane argmin over 512 codes.
    //      dist' = ||d||^2 - 2 mu.d  (row-constant ||mu||^2 dropped:
    //      argmin-invariant; fp32 error ~1e-5 << 2.5e-4 gap threshold).
    //      Strict < with ascending k == first-index tie-break (jnp.argmin).
    float best = FLT_MAX, sec = FLT_MAX;
    int   bk   = 0;
#pragma unroll 1
    for (int k4 = 0; k4 < K; k4 += 4) {
        const float4 nd4 = *reinterpret_cast<const float4*>(&nd_s[k4]);
#define CODE(J, ND) { \
        const float4* p = reinterpret_cast<const float4*>( \
            dbase + (size_t)(k4 + J) * E); \
        const float4 a0 = p[0], a1 = p[1], a2 = p[2], a3 = p[3]; \
        float dot = fdot4(a0, m0, 0.0f); \
        dot = fdot4(a1, m1, dot); \
        dot = fdot4(a2, m2, dot); \
        dot = fdot4(a3, m3, dot); \
        const float dist = fmaf(-2.0f, dot, ND); \
        sec = fminf(sec, fmaxf(best, dist)); \
        if (dist < best) { best = dist; bk = k4 + J; } }
        CODE(0, nd4.x) CODE(1, nd4.y) CODE(2, nd4.z) CODE(3, nd4.w)
#undef CODE
    }

    // ---- rare exact path: per-lane fp64 full re-scan when the fp32 gap is
    //      within 2.5e-4 (>=10x the worst-case combined fp32 error). Waves
    //      with no flagged lane skip via execz.
    if (sec - best < 2.5e-4f) {
        double bdd = DBL_MAX;
        int    bkk = 0;
        for (int k = 0; k < K; ++k) {
            const float4* p = reinterpret_cast<const float4*>(dbase + (size_t)k * E);
            const float4 a0 = p[0], a1 = p[1], a2 = p[2], a3 = p[3];
            double nd = dnrm4(a0, 0.0);
            nd = dnrm4(a1, nd); nd = dnrm4(a2, nd); nd = dnrm4(a3, nd);
            double dt = ddot4(a0, m0, 0.0);
            dt = ddot4(a1, m1, dt); dt = ddot4(a2, m2, dt); dt = ddot4(a3, m3, dt);
            const double dist = nd - 2.0 * dt;
            if (dist < bdd) { bdd = dist; bkk = k; }
        }
        bk = bkk;
    }

    // ---- z / zq epilogue: zq = dict[bk]; z = mu + (zq - mu) in fp32,
    //      op-for-op like the reference. 64 B per lane = full lines.
    {
        const float4* qp = reinterpret_cast<const float4*>(dbase + (size_t)bk * E);
        const float4 q0 = qp[0], q1 = qp[1], q2 = qp[2], q3 = qp[3];
        float4* zo  = reinterpret_cast<float4*>(z  + (size_t)b * MUS + c * E);
        float4* zqo = reinterpret_cast<float4*>(zq + (size_t)b * MUS + c * E);
        zqo[0] = q0; zqo[1] = q1; zqo[2] = q2; zqo[3] = q3;
        float4 r0, r1, r2, r3;
        r0.x = m0.x + (q0.x - m0.x); r0.y = m0.y + (q0.y - m0.y);
        r0.z = m0.z + (q0.z - m0.z); r0.w = m0.w + (q0.w - m0.w);
        r1.x = m1.x + (q1.x - m1.x); r1.y = m1.y + (q1.y - m1.y);
        r1.z = m1.z + (q1.z - m1.z); r1.w = m1.w + (q1.w - m1.w);
        r2.x = m2.x + (q2.x - m2.x); r2.y = m2.y + (q2.y - m2.y);
        r2.z = m2.z + (q2.z - m2.z); r2.w = m2.w + (q2.w - m2.w);
        r3.x = m3.x + (q3.x - m3.x); r3.y = m3.y + (q3.y - m3.y);
        r3.z = m3.z + (q3.z - m3.z); r3.w = m3.w + (q3.w - m3.w);
        zo[0] = r0; zo[1] = r1; zo[2] = r2; zo[3] = r3;
    }

    // ---- order the 1.0 scatter after this wave's zero-fill, then write it.
    //      The fill lines are L2-dirty-hot, so the scatter costs no extra HBM.
    asm volatile("s_waitcnt vmcnt(0)" ::: "memory");
    oh[((size_t)b * C + c) * K + bk] = 1.0f;
}

extern "C" void kernel_launch(void* const* d_in, const int* in_sizes, int n_in,
                              void* d_out, int out_size, void* d_ws, size_t ws_size,
                              hipStream_t stream)
{
    const float* mu   = (const float*)d_in[0];
    const float* dict = (const float*)d_in[1];

    float* z  = (float*)d_out;                 // (B, C*E)
    float* zq = z  + (size_t)B * C * E;        // (B, C*E)
    float* oh = zq + (size_t)B * C * E;        // (B, C, K)

    dim3 grid(C, B / RPB);                     // (512, 2) = 1024 blocks
    vq_kernel<<<grid, 256, 0, stream>>>(mu, dict, z, zq, oh);
}

// Round 5
// 698.792 us; speedup vs baseline: 1.2315x; 1.2315x over previous
//
#include <hip/hip_runtime.h>
#include <float.h>

// Problem constants (from reference file)
constexpr int C   = 512;           // DIM_CODES
constexpr int K   = 512;           // DICT_SIZE
constexpr int E   = 16;           // EMBED_DIM
constexpr int B   = 512;           // BATCH
constexpr int RPB = 256;           // rows (batches) per block = blockDim
constexpr int MUS = C * E;         // 8192, mu row stride

__device__ __forceinline__ float fdot4(const float4 a, const float4 b, float acc) {
    acc = fmaf(a.x, b.x, acc);
    acc = fmaf(a.y, b.y, acc);
    acc = fmaf(a.z, b.z, acc);
    acc = fmaf(a.w, b.w, acc);
    return acc;
}
__device__ __forceinline__ double ddot4(const float4 a, const float4 b, double acc) {
    return acc + ((double)a.x * b.x + (double)a.y * b.y
                + (double)a.z * b.z + (double)a.w * b.w);
}
__device__ __forceinline__ double dnrm4(const float4 a, double acc) {
    return acc + ((double)a.x * a.x + (double)a.y * a.y
                + (double)a.z * a.z + (double)a.w * a.w);
}

// Thread <-> row mapping (round 4), plus two fixes for the 22%-VALUBusy stall:
//  (a) dict slice staged in LDS once (coalesced), k-loop reads it via
//      wave-uniform broadcast ds_read_b128 (conflict-free, no VMEM latency
//      in the hot loop);
//  (b) the one_hot zero-fill is interleaved ONE store per k-iteration
//      (128 iters <-> 128 fill stores per wave), so the dominant 552 MB
//      store stream overlaps compute instead of bursting at the start and
//      stalling every wave on a full vmem queue.
// LDS: 32 KB dict + 2 KB norms = 34 KB -> 4 blocks/CU (136/160 KB).
__launch_bounds__(256, 4)
__global__ void vq_kernel(const float* __restrict__ mu,
                          const float* __restrict__ dict,
                          float* __restrict__ z,
                          float* __restrict__ zq,
                          float* __restrict__ oh)
{
    const int c    = blockIdx.x;
    const int tid  = threadIdx.x;
    const int lane = tid & 63;
    const int b    = blockIdx.y * RPB + tid;           // this thread's row
    const int b0w  = blockIdx.y * RPB + (tid & ~63);   // this wave's first row

    __shared__ float sd[K * E];    // dict slice, 32 KB
    __shared__ float snd[K];       // per-code ||d||^2, 2 KB

    const float* __restrict__ dbase = dict + (size_t)c * K * E;

    // ---- this thread's mu row -> registers (issue early)
    const float4* mp = reinterpret_cast<const float4*>(mu + (size_t)b * MUS + c * E);
    const float4 m0 = mp[0], m1 = mp[1], m2 = mp[2], m3 = mp[3];

    // ---- stage dict slice into LDS: linear mapping, perfectly coalesced
    //      global reads (1 KB/instr/wave); LDS writes are BW-bound only.
    {
        const float4* g = reinterpret_cast<const float4*>(dbase);
        float4*       l = reinterpret_cast<float4*>(sd);
#pragma unroll
        for (int rep = 0; rep < 8; ++rep)
            l[tid + rep * 256] = g[tid + rep * 256];
    }
    __syncthreads();

    // ---- per-code norms (thread t -> codes t, t+256), one-time
#pragma unroll
    for (int rep = 0; rep < 2; ++rep) {
        const int k = tid + rep * 256;
        const float4* p = reinterpret_cast<const float4*>(&sd[k * E]);
        const float4 a0 = p[0], a1 = p[1], a2 = p[2], a3 = p[3];
        float s = fdot4(a0, a0, 0.0f);
        s = fdot4(a1, a1, s);
        s = fdot4(a2, a2, s);
        s = fdot4(a3, a3, s);
        snd[k] = s;
    }
    __syncthreads();

    // ---- k-loop: per-lane argmin over 512 codes (LDS broadcast reads),
    //      one interleaved one_hot zero-fill store per iteration.
    //      dist' = ||d||^2 - 2 mu.d (row-constant ||mu||^2 dropped:
    //      argmin-invariant). Strict < + ascending k == first-index
    //      tie-break (jnp.argmin). Same decision function as round 4
    //      (absmax 0).
    float4* ohw = reinterpret_cast<float4*>(oh + ((size_t)b0w * C + c) * K);
    const size_t rs4 = (size_t)C * K / 4;          // one b-row in float4 units
    const float4 zero4 = make_float4(0.f, 0.f, 0.f, 0.f);

    float best = FLT_MAX, sec = FLT_MAX;
    int   bk   = 0;
#pragma unroll 1
    for (int i = 0; i < K / 4; ++i) {
        // fill store: row (i>>1) of this wave's 64 rows, half (i&1).
        // 1 KB contiguous across the wave; address = lane base + uniform off.
        ohw[(size_t)(i >> 1) * rs4 + (size_t)((i & 1) * 64 + lane)] = zero4;

        const int k4 = i * 4;
        const float4 nd4 = *reinterpret_cast<const float4*>(&snd[k4]);
#define CODE(J, ND) { \
        const float4* p = reinterpret_cast<const float4*>(&sd[(k4 + J) * E]); \
        const float4 a0 = p[0], a1 = p[1], a2 = p[2], a3 = p[3]; \
        float dot = fdot4(a0, m0, 0.0f); \
        dot = fdot4(a1, m1, dot); \
        dot = fdot4(a2, m2, dot); \
        dot = fdot4(a3, m3, dot); \
        const float dist = fmaf(-2.0f, dot, ND); \
        sec = fminf(sec, fmaxf(best, dist)); \
        if (dist < best) { best = dist; bk = k4 + J; } }
        CODE(0, nd4.x) CODE(1, nd4.y) CODE(2, nd4.z) CODE(3, nd4.w)
#undef CODE
    }

    // ---- rare exact path: per-lane fp64 full re-scan (LDS holds identical
    //      bits to global) when fp32 gap < 2.5e-4 (>=10x worst-case fp32
    //      error). Waves with no flagged lane skip via execz.
    if (sec - best < 2.5e-4f) {
        double bdd = DBL_MAX;
        int    bkk = 0;
        for (int k = 0; k < K; ++k) {
            const float4* p = reinterpret_cast<const float4*>(&sd[k * E]);
            const float4 a0 = p[0], a1 = p[1], a2 = p[2], a3 = p[3];
            double nd = dnrm4(a0, 0.0);
            nd = dnrm4(a1, nd); nd = dnrm4(a2, nd); nd = dnrm4(a3, nd);
            double dt = ddot4(a0, m0, 0.0);
            dt = ddot4(a1, m1, dt); dt = ddot4(a2, m2, dt); dt = ddot4(a3, m3, dt);
            const double dist = nd - 2.0 * dt;
            if (dist < bdd) { bdd = dist; bkk = k; }
        }
        bk = bkk;
    }

    // ---- z / zq epilogue: zq = dict[bk] (LDS gather, one-time);
    //      z = mu + (zq - mu) in fp32, op-for-op like the reference.
    {
        const float4* qp = reinterpret_cast<const float4*>(&sd[bk * E]);
        const float4 q0 = qp[0], q1 = qp[1], q2 = qp[2], q3 = qp[3];
        float4* zo  = reinterpret_cast<float4*>(z  + (size_t)b * MUS + c * E);
        float4* zqo = reinterpret_cast<float4*>(zq + (size_t)b * MUS + c * E);
        zqo[0] = q0; zqo[1] = q1; zqo[2] = q2; zqo[3] = q3;
        float4 r0, r1, r2, r3;
        r0.x = m0.x + (q0.x - m0.x); r0.y = m0.y + (q0.y - m0.y);
        r0.z = m0.z + (q0.z - m0.z); r0.w = m0.w + (q0.w - m0.w);
        r1.x = m1.x + (q1.x - m1.x); r1.y = m1.y + (q1.y - m1.y);
        r1.z = m1.z + (q1.z - m1.z); r1.w = m1.w + (q1.w - m1.w);
        r2.x = m2.x + (q2.x - m2.x); r2.y = m2.y + (q2.y - m2.y);
        r2.z = m2.z + (q2.z - m2.z); r2.w = m2.w + (q2.w - m2.w);
        r3.x = m3.x + (q3.x - m3.x); r3.y = m3.y + (q3.y - m3.y);
        r3.z = m3.z + (q3.z - m3.z); r3.w = m3.w + (q3.w - m3.w);
        zo[0] = r0; zo[1] = r1; zo[2] = r2; zo[3] = r3;
    }

    // ---- order the 1.0 scatter after this wave's own fill stores (VMEM
    //      stores may complete out of order), then write it.
    asm volatile("s_waitcnt vmcnt(0)" ::: "memory");
    oh[((size_t)b * C + c) * K + bk] = 1.0f;
}

extern "C" void kernel_launch(void* const* d_in, const int* in_sizes, int n_in,
                              void* d_out, int out_size, void* d_ws, size_t ws_size,
                              hipStream_t stream)
{
    const float* mu   = (const float*)d_in[0];
    const float* dict = (const float*)d_in[1];

    float* z  = (float*)d_out;                 // (B, C*E)
    float* zq = z  + (size_t)B * C * E;        // (B, C*E)
    float* oh = zq + (size_t)B * C * E;        // (B, C, K)

    dim3 grid(C, B / RPB);                     // (512, 2) = 1024 blocks
    vq_kernel<<<grid, 256, 0, stream>>>(mu, dict, z, zq, oh);
}